// Round 7
// baseline (437.339 us; speedup 1.0000x reference)
//
#include <hip/hip_runtime.h>
#include <math.h>

#define NB   2048
#define DIN  784
#define HN   256
#define NOUT 10
#define OSTR (HN + HN + NOUT)   // 522

// Per-block LDS: 8 rows per block (2 rows per wave). ~69 KB (2 blocks/CU fit).
struct Smem {
  float4  sup[8][HN];      // 32 KB: (node, u, parent-logit, q or NaN) per j
  double2 tab[65];         // 1040 B
  float   scr[8][16 * 20]; // 10 KB fold scratch (exact init + rare fallback only)
  float   h2o[8][HN];      // 8 KB
  float   h1n[8][HN];      // 8 KB
  float   tmp[8][HN];      // 8 KB
  float   yv [8][16];      // 512 B
};

// ---- bitwise replica of numpy's SIMD float32 exp (exact/fallback path) -----
__device__ __forceinline__ float np_expf(float xf) {
  float q = __fmul_rn(xf, 1.442695040888963f);
  q = __fadd_rn(q, 12582912.0f);
  q = __fsub_rn(q, 12582912.0f);
  float x = __builtin_fmaf(q, -6.93145752e-1f, xf);
  x = __builtin_fmaf(q, -1.42860677e-6f, x);
  float num = __builtin_fmaf(x, 5.082762527590693718096e-04f,
                                6.757896990527504603057e-03f);
  num = __builtin_fmaf(num, x, 5.114512081637298353406e-02f);
  num = __builtin_fmaf(num, x, 2.473615434895520810817e-01f);
  num = __builtin_fmaf(num, x, 7.257664613233124478488e-01f);
  num = __builtin_fmaf(num, x, 9.999999999980870924916e-01f);
  float den = __builtin_fmaf(x, 2.159509375685829852307e-02f,
                                -2.742335390411667452936e-01f);
  den = __builtin_fmaf(den, x, 1.0f);
  float r = __fdiv_rn(num, den);
  int qi = (int)q;
  return __fmul_rn(r, __int_as_float((qi + 127) << 23));
}

// fp64 log1p for e in (0,1] — bitwise replica class (exact/fallback path)
__device__ __forceinline__ float np_log1pf(float ef, const double2* __restrict__ tab) {
  if (ef < 0x1p-29f) return ef;
  double t  = 1.0 + (double)ef;
  double kd = rint(t * 64.0);
  int   idx = (int)kd - 64;
  double2 te = tab[idx];
  double c  = kd * 0.015625;
  double s  = (t - c) * te.y;
  double p  = fma(s, -1.0/6.0, 0.2);
  p = fma(p, s, -0.25);
  p = fma(p, s,  1.0/3.0);
  p = fma(p, s, -0.5);
  p = fma(p, s,  1.0);
  p = p * s;
  return (float)(te.x + p);
}

// sigmoid-CE, numpy op order  [exact]
__device__ __forceinline__ float ce32(float l, float label, const double2* __restrict__ tab) {
  float t3 = __fsub_rn(fmaxf(l, 0.0f), __fmul_rn(l, label));
  return __fadd_rn(t3, np_log1pf(np_expf(-fabsf(l)), tab));
}

// Exact decision u < prob  [exact/fallback path]
__device__ __forceinline__ bool decide(float u, float ez) {
  float w = __fadd_rn(1.0f, ez);
  float d = __builtin_fmaf(u, w, -1.0f);
  if (__builtin_expect(fabsf(d) < 1e-5f, 0)) {
    float prob = __fdiv_rn(1.0f, w);
    return u < prob;
  }
  return d < 0.0f;
}

// lane data movement (bitwise-safe)
template<int CTRL> __device__ __forceinline__ float dppx(float v) {
  return __int_as_float(__builtin_amdgcn_mov_dpp(__float_as_int(v), CTRL, 0xF, 0xF, true));
}
__device__ __forceinline__ float rdl(float v, int l) {
  return __int_as_float(__builtin_amdgcn_readlane(__float_as_int(v), l));
}

// numpy pairwise sum over 10 on lanes 0..9  [exact/fallback]
__device__ __forceinline__ float sum10(float c) {
  float c0 = rdl(c, 0), c1 = rdl(c, 1), c2 = rdl(c, 2), c3 = rdl(c, 3);
  float c4 = rdl(c, 4), c5 = rdl(c, 5), c6 = rdl(c, 6), c7 = rdl(c, 7);
  float c8 = rdl(c, 8), c9 = rdl(c, 9);
  float t = __fadd_rn(__fadd_rn(__fadd_rn(c0, c1), __fadd_rn(c2, c3)),
                      __fadd_rn(__fadd_rn(c4, c5), __fadd_rn(c6, c7)));
  t = __fadd_rn(t, c8);
  t = __fadd_rn(t, c9);
  return t;
}

// numpy pairwise sum over 256 children via LDS transpose  [exact/fallback]
__device__ __forceinline__ float fold256_lds(const float c[4], float* __restrict__ scrw,
                                             int idx, int g) {
  *reinterpret_cast<float4*>(scrw + idx * 20 + 4 * g) = make_float4(c[0], c[1], c[2], c[3]);
  const float4* rp = reinterpret_cast<const float4*>(scrw + idx * 20);
  float4 q0 = rp[0], q1 = rp[1], q2 = rp[2], q3 = rp[3];
  float r = q0.x;
  r = __fadd_rn(r, q0.y); r = __fadd_rn(r, q0.z); r = __fadd_rn(r, q0.w);
  r = __fadd_rn(r, q1.x); r = __fadd_rn(r, q1.y); r = __fadd_rn(r, q1.z); r = __fadd_rn(r, q1.w);
  r = __fadd_rn(r, q2.x); r = __fadd_rn(r, q2.y); r = __fadd_rn(r, q2.z); r = __fadd_rn(r, q2.w);
  r = __fadd_rn(r, q3.x); r = __fadd_rn(r, q3.y); r = __fadd_rn(r, q3.z); r = __fadd_rn(r, q3.w);
  r = __fadd_rn(r, dppx<0xB1>(r));
  r = __fadd_rn(r, dppx<0x4E>(r));
  float B0 = rdl(r, 0), B1 = rdl(r, 4), B2 = rdl(r, 8), B3 = rdl(r, 12);
  return __fadd_rn(__fadd_rn(B0, B1), __fadd_rn(B2, B3));
}

// ---- FAST path helpers ------------------------------------------------------
__device__ __forceinline__ float fast_sum256(float loc) {
  float r = loc;
  r = r + dppx<0xB1>(r);                  // quad xor 1
  r = r + dppx<0x4E>(r);                  // quad xor 2
  r = r + dppx<0x124>(r);                 // row_ror:4
  r = r + dppx<0x128>(r);                 // row_ror:8
  r = r + dppx<0x142>(r);                 // row_bcast15
  r = r + dppx<0x143>(r);                 // row_bcast31
  return rdl(r, 63);
}
__device__ __forceinline__ float fast_sum10(float loc) {
  float r = loc;
  r = r + dppx<0xB1>(r);
  r = r + dppx<0x4E>(r);
  r = r + dppx<0x124>(r);
  r = r + dppx<0x128>(r);
  return rdl(r, 0);
}

// z-space threshold; NaN for extreme u routes to exact path.
__device__ __forceinline__ float lu_of(float u) {
  if (u < 1e-4f || u > 0.9999f) return __int_as_float(0x7FC00000);
  return __logf(u) - __logf(__fsub_rn(1.0f, u));
}
__device__ __forceinline__ float q_of(float node, float pl, float u) {
  float lu = lu_of(u);
  float pq = __fsub_rn(pl, lu);
  return (node != 0.0f) ? pq : -pq;
}

#define ZBAND 0.05f
#define LN2F  0.6931471805599453f

// Exact near-boundary replica, 256-child layer. Updates nlv, S_c; returns nw.
__device__ __forceinline__ bool exact_decide256(
    float node, float u, float pl, float nlv[4], const int smk[4],
    const float wc[4], float* __restrict__ scrw, int idx, int g,
    const double2* __restrict__ tab, float& S_c)
{
  float one_m = __fsub_rn(1.0f, node);
  float nl0[4], nl1[4], c0i[4], c1i[4];
  #pragma unroll
  for (int c = 0; c < 4; ++c) {
    float nv = (smk[c] != 0) ? 1.0f : 0.0f;
    nl0[c] = __fsub_rn(nlv[c], __fmul_rn(node,  wc[c]));
    nl1[c] = __fadd_rn(nlv[c], __fmul_rn(one_m, wc[c]));
    c0i[c] = ce32(nl0[c], nv, tab);
    c1i[c] = ce32(nl1[c], nv, tab);
  }
  float S0e = fold256_lds(c0i, scrw, idx, g);
  float S1e = fold256_lds(c1i, scrw, idx, g);
  float ze  = __fsub_rn(__fadd_rn(pl, -S1e), -S0e);
  bool nw = decide(u, np_expf(-ze));
  S_c = nw ? S1e : S0e;
  #pragma unroll
  for (int c = 0; c < 4; ++c) nlv[c] = nw ? nl1[c] : nl0[c];
  return nw;
}

// Exact near-boundary replica, 10-child layer. Updates nlo, S_c1; returns nw.
__device__ __forceinline__ bool exact_decide10(
    float node, float u, float pl, float& nlo, float nvy, float w, bool lact,
    const double2* __restrict__ tab, float& S_c1)
{
  float one_m = __fsub_rn(1.0f, node);
  float nl0 = __fsub_rn(nlo, __fmul_rn(node,  w));
  float nl1 = __fadd_rn(nlo, __fmul_rn(one_m, w));
  float c0 = lact ? ce32(nl0, nvy, tab) : 0.0f;
  float c1 = lact ? ce32(nl1, nvy, tab) : 0.0f;
  float S0e = sum10(c0);
  float S1e = sum10(c1);
  float ze  = __fsub_rn(__fadd_rn(pl, -S1e), -S0e);
  bool nw = decide(u, np_expf(-ze));
  S_c1 = nw ? S1e : S0e;
  nlo  = nw ? nl1 : nl0;
  return nw;
}

__global__ __launch_bounds__(256) void stoch_mlp(
    const float* __restrict__ x,  const int* __restrict__ h1,
    const int* __restrict__ h2,   const int* __restrict__ y,
    const float* __restrict__ W1, const float* __restrict__ b1,
    const float* __restrict__ W2, const float* __restrict__ b2,
    const float* __restrict__ Wo, const float* __restrict__ bo,
    const float* __restrict__ u1, const float* __restrict__ u2,
    float* __restrict__ out)
{
  __shared__ Smem sm;
  const int t    = threadIdx.x;
  const int lane = t & 63;
  const int wid  = t >> 6;
  const int rAl  = 2 * wid;           // local row ids (2 rows per wave)
  const int rBl  = 2 * wid + 1;
  const int bbase = blockIdx.x * 8;
  const int bA   = bbase + rAl;
  const int bB   = bbase + rBl;

  // ---- phase 1: tables, states, pl1 = x@W1 (BLAS fp32, 8 rows/block) ------
  if (t < 65) {
    double c = (double)(t + 64) * 0.015625;
    sm.tab[t] = make_double2(log(c), 64.0 / (double)(t + 64));
  }
  for (int j = lane; j < HN; j += 64) {
    sm.h2o[rAl][j] = (float)h2[(size_t)bA * HN + j];
    sm.h2o[rBl][j] = (float)h2[(size_t)bB * HN + j];
  }
  if (lane < 16) {
    sm.yv[rAl][lane] = (lane < NOUT) ? (float)y[bA * NOUT + lane] : 0.0f;
    sm.yv[rBl][lane] = (lane < NOUT) ? (float)y[bB * NOUT + lane] : 0.0f;
  }
  {
    float a[8] = {0,0,0,0,0,0,0,0};     // sequential-k FMA chains, 8 rows
    const float* x0 = x + (size_t)bbase * DIN;
    float wk[8];                         // 8-deep W1 ring (order unchanged)
    #pragma unroll
    for (int i = 0; i < 8; ++i) wk[i] = W1[(size_t)i * HN + t];
    #pragma unroll 8
    for (int k = 0; k < DIN; ++k) {
      float w = wk[k & 7];
      int kp = (k + 8 < DIN) ? (k + 8) : 0;
      wk[k & 7] = W1[(size_t)kp * HN + t];
      #pragma unroll
      for (int r = 0; r < 8; ++r)
        a[r] = __builtin_fmaf(x0[(size_t)r * DIN + k], w, a[r]);
    }
    float bb = b1[t];
    float4 uv0 = *reinterpret_cast<const float4*>(u1 + (size_t)t * NB + bbase);
    float4 uv1 = *reinterpret_cast<const float4*>(u1 + (size_t)t * NB + bbase + 4);
    float uu[8] = {uv0.x, uv0.y, uv0.z, uv0.w, uv1.x, uv1.y, uv1.z, uv1.w};
    #pragma unroll
    for (int r = 0; r < 8; ++r) {
      float n  = (float)h1[(size_t)(bbase + r) * HN + t];
      float pl = __fadd_rn(a[r], bb);
      sm.sup[r][t] = make_float4(n, uu[r], pl, q_of(n, pl, uu[r]));
    }
  }
  __syncthreads();   // sup + tab + h2o written cross-wave

  const double2* tab = sm.tab;
  float* scrA = &sm.scr[rAl][0];
  float* scrB = &sm.scr[rBl][0];

  // nl-init = h1_old @ W2 + b2 (branchless fma == masked chain), shared W2 load
  {
    float accA[4] = {0,0,0,0}, accB[4] = {0,0,0,0};
    float4 wb[2];
    wb[0] = *reinterpret_cast<const float4*>(W2 + 4*lane);
    wb[1] = *reinterpret_cast<const float4*>(W2 + HN + 4*lane);
    #pragma unroll 2
    for (int j = 0; j < HN; ++j) {
      float4 wf = wb[j & 1];
      int jp = (j + 2) & (HN - 1);
      wb[j & 1] = *reinterpret_cast<const float4*>(W2 + (size_t)jp * HN + 4*lane);
      float nA = sm.sup[rAl][j].x;
      float nB = sm.sup[rBl][j].x;
      accA[0] = __builtin_fmaf(nA, wf.x, accA[0]);
      accA[1] = __builtin_fmaf(nA, wf.y, accA[1]);
      accA[2] = __builtin_fmaf(nA, wf.z, accA[2]);
      accA[3] = __builtin_fmaf(nA, wf.w, accA[3]);
      accB[0] = __builtin_fmaf(nB, wf.x, accB[0]);
      accB[1] = __builtin_fmaf(nB, wf.y, accB[1]);
      accB[2] = __builtin_fmaf(nB, wf.z, accB[2]);
      accB[3] = __builtin_fmaf(nB, wf.w, accB[3]);
    }
    float4 bv = *reinterpret_cast<const float4*>(b2 + 4*lane);
    *reinterpret_cast<float4*>(&sm.tmp[rAl][4*lane]) =
        make_float4(__fadd_rn(accA[0], bv.x), __fadd_rn(accA[1], bv.y),
                    __fadd_rn(accA[2], bv.z), __fadd_rn(accA[3], bv.w));
    *reinterpret_cast<float4*>(&sm.tmp[rBl][4*lane]) =
        make_float4(__fadd_rn(accB[0], bv.x), __fadd_rn(accB[1], bv.y),
                    __fadd_rn(accB[2], bv.z), __fadd_rn(accB[3], bv.w));
  }
  // tmp wave-private; same-wave DS ordering -> no barrier

  // ---- phase 2: layer-0 scan — 2 rows interleaved, 4 children/lane/row ----
  const int idx  = lane & 15;
  const int g    = lane >> 4;
  const int half = idx >> 3;
  const int jacc = idx & 7;
  const int kb   = half * 128 + (4 * g) * 8 + jacc;

  float nlvA[4], nlvB[4];
  int   smkA[4], smkB[4];
  #pragma unroll
  for (int i = 0; i < 4; ++i) {
    int k = kb + i * 8;
    nlvA[i] = sm.tmp[rAl][k];
    nlvB[i] = sm.tmp[rBl][k];
    smkA[i] = (sm.h2o[rAl][k] != 0.0f) ? (int)0x80000000 : 0;
    smkB[i] = (sm.h2o[rBl][k] != 0.0f) ? (int)0x80000000 : 0;
  }
  float S_cA, S_cB;                    // carried CE sums (fast between fallbacks)
  {
    float ciA[4], ciB[4];              // exact init (once): tight anchor
    #pragma unroll
    for (int i = 0; i < 4; ++i) {
      float nvA = (smkA[i] != 0) ? 1.0f : 0.0f;
      float nvB = (smkB[i] != 0) ? 1.0f : 0.0f;
      ciA[i] = ce32(nlvA[i], nvA, tab);
      ciB[i] = ce32(nlvB[i], nvB, tab);
    }
    S_cA = fold256_lds(ciA, scrA, idx, g);
    S_cB = fold256_lds(ciB, scrB, idx, g);
  }

  {
    // 2-deep rings: sup per row; W2 row shared between the two rows
    float4 srA[2], srB[2];
    float wring[2][4];
    srA[0] = sm.sup[rAl][0]; srA[1] = sm.sup[rAl][1];
    srB[0] = sm.sup[rBl][0]; srB[1] = sm.sup[rBl][1];
    #pragma unroll
    for (int c = 0; c < 4; ++c) {
      wring[0][c] = W2[kb + c * 8];
      wring[1][c] = W2[(size_t)HN + kb + c * 8];
    }
    #pragma unroll 2
    for (int j = 0; j < HN; ++j) {
      const int s = j & 1;
      float4 scA = srA[s], scB = srB[s];
      float wc[4];
      #pragma unroll
      for (int c = 0; c < 4; ++c) wc[c] = wring[s][c];
      int jp = (j + 2) & (HN - 1);
      srA[s] = sm.sup[rAl][jp];
      srB[s] = sm.sup[rBl][jp];
      #pragma unroll
      for (int c = 0; c < 4; ++c) wring[s][c] = W2[(size_t)jp * HN + kb + c * 8];

      // row A per-child (fresh side only; stale side == nlv bitwise)
      int ndmA = (scA.x != 0.0f) ? (int)0x80000000 : 0;
      float frA[4], t3A[4], avA[4];
      #pragma unroll
      for (int c = 0; c < 4; ++c) {
        float ws = __int_as_float(__float_as_int(wc[c]) ^ ndmA);
        frA[c] = __fadd_rn(nlvA[c], ws);
        float sl = __int_as_float(__float_as_int(frA[c]) ^ smkA[c]);
        t3A[c] = fmaxf(sl, 0.0f);
        avA[c] = __fadd_rn(1.0f, __expf(-fabsf(frA[c])));
      }
      // row B per-child
      int ndmB = (scB.x != 0.0f) ? (int)0x80000000 : 0;
      float frB[4], t3B[4], avB[4];
      #pragma unroll
      for (int c = 0; c < 4; ++c) {
        float ws = __int_as_float(__float_as_int(wc[c]) ^ ndmB);
        frB[c] = __fadd_rn(nlvB[c], ws);
        float sl = __int_as_float(__float_as_int(frB[c]) ^ smkB[c]);
        t3B[c] = fmaxf(sl, 0.0f);
        avB[c] = __fadd_rn(1.0f, __expf(-fabsf(frB[c])));
      }
      float TA = (t3A[0] + t3A[1]) + (t3A[2] + t3A[3]);
      float PA = (avA[0] * avA[1]) * (avA[2] * avA[3]);
      float TB = (t3B[0] + t3B[1]) + (t3B[2] + t3B[3]);
      float PB = (avB[0] * avB[1]) * (avB[2] * avB[3]);
      float FA = fast_sum256(__builtin_fmaf(LN2F, __log2f(PA), TA));
      float FB = fast_sum256(__builtin_fmaf(LN2F, __log2f(PB), TB));

      // decide row A
      float ddA = (FA - S_cA) + scA.w;           // NaN q -> exact path
      if (__builtin_expect(!(fabsf(ddA) >= ZBAND), 0)) {
        bool nw = exact_decide256(scA.x, scA.y, scA.z, nlvA, smkA, wc,
                                  scrA, idx, g, tab, S_cA);
        if (lane == 0) sm.h1n[rAl][j] = nw ? 1.0f : 0.0f;
      } else {
        bool flip = ddA < 0.0f;
        S_cA = flip ? FA : S_cA;
        #pragma unroll
        for (int c = 0; c < 4; ++c) nlvA[c] = flip ? frA[c] : nlvA[c];
        if (lane == 0) sm.h1n[rAl][j] = flip ? __fsub_rn(1.0f, scA.x) : scA.x;
      }
      // decide row B
      float ddB = (FB - S_cB) + scB.w;
      if (__builtin_expect(!(fabsf(ddB) >= ZBAND), 0)) {
        bool nw = exact_decide256(scB.x, scB.y, scB.z, nlvB, smkB, wc,
                                  scrB, idx, g, tab, S_cB);
        if (lane == 0) sm.h1n[rBl][j] = nw ? 1.0f : 0.0f;
      } else {
        bool flip = ddB < 0.0f;
        S_cB = flip ? FB : S_cB;
        #pragma unroll
        for (int c = 0; c < 4; ++c) nlvB[c] = flip ? frB[c] : nlvB[c];
        if (lane == 0) sm.h1n[rBl][j] = flip ? __fsub_rn(1.0f, scB.x) : scB.x;
      }
    }
  }
  // h1n wave-private; no barrier needed

  // ---- phase 3: pl2 = h1_new @ W2 + b2 (shared W2 load); repack staging ---
  {
    float accA[4] = {0,0,0,0}, accB[4] = {0,0,0,0};
    float4 wb[2];
    wb[0] = *reinterpret_cast<const float4*>(W2 + 4*lane);
    wb[1] = *reinterpret_cast<const float4*>(W2 + HN + 4*lane);
    #pragma unroll 2
    for (int j = 0; j < HN; ++j) {
      float4 wf = wb[j & 1];
      int jp = (j + 2) & (HN - 1);
      wb[j & 1] = *reinterpret_cast<const float4*>(W2 + (size_t)jp * HN + 4*lane);
      float nA = sm.h1n[rAl][j];
      float nB = sm.h1n[rBl][j];
      accA[0] = __builtin_fmaf(nA, wf.x, accA[0]);
      accA[1] = __builtin_fmaf(nA, wf.y, accA[1]);
      accA[2] = __builtin_fmaf(nA, wf.z, accA[2]);
      accA[3] = __builtin_fmaf(nA, wf.w, accA[3]);
      accB[0] = __builtin_fmaf(nB, wf.x, accB[0]);
      accB[1] = __builtin_fmaf(nB, wf.y, accB[1]);
      accB[2] = __builtin_fmaf(nB, wf.z, accB[2]);
      accB[3] = __builtin_fmaf(nB, wf.w, accB[3]);
    }
    float4 bv = *reinterpret_cast<const float4*>(b2 + 4*lane);
    float pA[4] = {__fadd_rn(accA[0], bv.x), __fadd_rn(accA[1], bv.y),
                   __fadd_rn(accA[2], bv.z), __fadd_rn(accA[3], bv.w)};
    float pB[4] = {__fadd_rn(accB[0], bv.x), __fadd_rn(accB[1], bv.y),
                   __fadd_rn(accB[2], bv.z), __fadd_rn(accB[3], bv.w)};
    #pragma unroll
    for (int i = 0; i < 4; ++i) {
      int j = 4 * lane + i;
      float uA = u2[(size_t)j * NB + bA];
      float uB = u2[(size_t)j * NB + bB];
      float nA = sm.h2o[rAl][j];
      float nB = sm.h2o[rBl][j];
      sm.sup[rAl][j] = make_float4(nA, uA, pA[i], q_of(nA, pA[i], uA));
      sm.sup[rBl][j] = make_float4(nB, uB, pB[i], q_of(nB, pB[i], uB));
    }
  }

  // layer-1 init: nlo = h2_old @ Wout + bout (shared Wo load)
  const bool lact = (lane < NOUT);
  float nvyA = lact ? sm.yv[rAl][lane] : 0.0f;
  float nvyB = lact ? sm.yv[rBl][lane] : 0.0f;
  float nloA, nloB;
  {
    float aA = 0.0f, aB = 0.0f;
    float wr[2];
    wr[0] = lact ? Wo[lane] : 0.0f;
    wr[1] = lact ? Wo[NOUT + lane] : 0.0f;
    #pragma unroll 2
    for (int j = 0; j < HN; ++j) {
      float wvv = wr[j & 1];
      int jp = (j + 2) & (HN - 1);
      wr[j & 1] = lact ? Wo[jp * NOUT + lane] : 0.0f;
      aA = __builtin_fmaf(sm.h2o[rAl][j], wvv, aA);
      aB = __builtin_fmaf(sm.h2o[rBl][j], wvv, aB);
    }
    float bov = lact ? bo[lane] : 0.0f;
    nloA = __fadd_rn(aA, bov);
    nloB = __fadd_rn(aB, bov);
  }
  float S_c1A = sum10(lact ? ce32(nloA, nvyA, tab) : 0.0f);
  float S_c1B = sum10(lact ? ce32(nloB, nvyB, tab) : 0.0f);
  const int sykA = (nvyA != 0.0f) ? (int)0x80000000 : 0;
  const int sykB = (nvyB != 0.0f) ? (int)0x80000000 : 0;

  // ---- phase 4: layer-1 scan — 2 rows interleaved -------------------------
  {
    float4 srA[2], srB[2];
    float wos[2];
    srA[0] = sm.sup[rAl][0]; srA[1] = sm.sup[rAl][1];
    srB[0] = sm.sup[rBl][0]; srB[1] = sm.sup[rBl][1];
    wos[0] = lact ? Wo[lane] : 0.0f;
    wos[1] = lact ? Wo[NOUT + lane] : 0.0f;
    #pragma unroll 2
    for (int j = 0; j < HN; ++j) {
      const int s = j & 1;
      float4 scA = srA[s], scB = srB[s];
      float w0s = wos[s];
      int jp = (j + 2) & (HN - 1);
      srA[s] = sm.sup[rAl][jp];
      srB[s] = sm.sup[rBl][jp];
      wos[s] = lact ? Wo[jp * NOUT + lane] : 0.0f;

      // row A
      int ndmA = (scA.x != 0.0f) ? (int)0x80000000 : 0;
      float wsA = __int_as_float(__float_as_int(w0s) ^ ndmA);
      float frA = __fadd_rn(nloA, wsA);
      float slA = __int_as_float(__float_as_int(frA) ^ sykA);
      float pAc = __log2f(__fadd_rn(1.0f, __expf(-fabsf(frA))));
      float locA = lact ? __builtin_fmaf(LN2F, pAc, fmaxf(slA, 0.0f)) : 0.0f;
      // row B
      int ndmB = (scB.x != 0.0f) ? (int)0x80000000 : 0;
      float wsB = __int_as_float(__float_as_int(w0s) ^ ndmB);
      float frB = __fadd_rn(nloB, wsB);
      float slB = __int_as_float(__float_as_int(frB) ^ sykB);
      float pBc = __log2f(__fadd_rn(1.0f, __expf(-fabsf(frB))));
      float locB = lact ? __builtin_fmaf(LN2F, pBc, fmaxf(slB, 0.0f)) : 0.0f;

      float FA = fast_sum10(locA);
      float FB = fast_sum10(locB);

      // decide row A
      float ddA = (FA - S_c1A) + scA.w;
      if (__builtin_expect(!(fabsf(ddA) >= ZBAND), 0)) {
        bool nw = exact_decide10(scA.x, scA.y, scA.z, nloA, nvyA, w0s, lact,
                                 tab, S_c1A);
        if (lane == 0) out[(size_t)bA * OSTR + HN + j] = nw ? 1.0f : 0.0f;
      } else {
        bool flip = ddA < 0.0f;
        S_c1A = flip ? FA : S_c1A;
        nloA  = flip ? frA : nloA;
        if (lane == 0) out[(size_t)bA * OSTR + HN + j] =
            flip ? __fsub_rn(1.0f, scA.x) : scA.x;
      }
      // decide row B
      float ddB = (FB - S_c1B) + scB.w;
      if (__builtin_expect(!(fabsf(ddB) >= ZBAND), 0)) {
        bool nw = exact_decide10(scB.x, scB.y, scB.z, nloB, nvyB, w0s, lact,
                                 tab, S_c1B);
        if (lane == 0) out[(size_t)bB * OSTR + HN + j] = nw ? 1.0f : 0.0f;
      } else {
        bool flip = ddB < 0.0f;
        S_c1B = flip ? FB : S_c1B;
        nloB  = flip ? frB : nloB;
        if (lane == 0) out[(size_t)bB * OSTR + HN + j] =
            flip ? __fsub_rn(1.0f, scB.x) : scB.x;
      }
    }
  }

  // ---- phase 5: outputs ---------------------------------------------------
  float* orA = out + (size_t)bA * OSTR;
  float* orB = out + (size_t)bB * OSTR;
  for (int j = lane; j < HN; j += 64) {
    orA[j] = sm.h1n[rAl][j];
    orB[j] = sm.h1n[rBl][j];
  }
  if (lact) {
    orA[2*HN + lane] = nloA;
    orB[2*HN + lane] = nloB;
  }
}

extern "C" void kernel_launch(void* const* d_in, const int* in_sizes, int n_in,
                              void* d_out, int out_size, void* d_ws, size_t ws_size,
                              hipStream_t stream) {
  const float* x  = (const float*)d_in[0];
  const int*   h1 = (const int*)  d_in[1];
  const int*   h2 = (const int*)  d_in[2];
  const int*   y  = (const int*)  d_in[3];
  const float* W1 = (const float*)d_in[4];
  const float* b1 = (const float*)d_in[5];
  const float* W2 = (const float*)d_in[6];
  const float* b2 = (const float*)d_in[7];
  const float* Wo = (const float*)d_in[8];
  const float* bo = (const float*)d_in[9];
  const float* u1 = (const float*)d_in[10];
  const float* u2 = (const float*)d_in[11];
  stoch_mlp<<<NB/8, 256, 0, stream>>>(x, h1, h2, y, W1, b1, W2, b2, Wo, bo, u1, u2,
                                      (float*)d_out);
}

// Round 8
// 322.992 us; speedup vs baseline: 1.3540x; 1.3540x over previous
//
#include <hip/hip_runtime.h>
#include <math.h>

#define NB   2048
#define DIN  784
#define HN   256
#define NOUT 10
#define OSTR (HN + HN + NOUT)   // 522

// Per-block LDS (h1n removed — h1 bits live in wave-uniform register masks).
struct Smem {
  float4  sup[4][HN];      // 16 KB: (node, u, parent-logit, q or NaN) per j
  double2 tab[65];         // 1040 B
  float   scr[4][16 * 20]; // 5 KB fold scratch (exact init + rare fallback only)
  float   h2o[4][HN];      // 4 KB
  float   tmp[4][HN];      // 4 KB nl-init redistribution
  float   yv [4][16];
};

// ---- bitwise replica of numpy's SIMD float32 exp (exact/fallback path) -----
__device__ __forceinline__ float np_expf(float xf) {
  float q = __fmul_rn(xf, 1.442695040888963f);
  q = __fadd_rn(q, 12582912.0f);
  q = __fsub_rn(q, 12582912.0f);
  float x = __builtin_fmaf(q, -6.93145752e-1f, xf);
  x = __builtin_fmaf(q, -1.42860677e-6f, x);
  float num = __builtin_fmaf(x, 5.082762527590693718096e-04f,
                                6.757896990527504603057e-03f);
  num = __builtin_fmaf(num, x, 5.114512081637298353406e-02f);
  num = __builtin_fmaf(num, x, 2.473615434895520810817e-01f);
  num = __builtin_fmaf(num, x, 7.257664613233124478488e-01f);
  num = __builtin_fmaf(num, x, 9.999999999980870924916e-01f);
  float den = __builtin_fmaf(x, 2.159509375685829852307e-02f,
                                -2.742335390411667452936e-01f);
  den = __builtin_fmaf(den, x, 1.0f);
  float r = __fdiv_rn(num, den);
  int qi = (int)q;
  return __fmul_rn(r, __int_as_float((qi + 127) << 23));
}

// fp64 log1p for e in (0,1] — bitwise replica class (exact/fallback path)
__device__ __forceinline__ float np_log1pf(float ef, const double2* __restrict__ tab) {
  if (ef < 0x1p-29f) return ef;
  double t  = 1.0 + (double)ef;
  double kd = rint(t * 64.0);
  int   idx = (int)kd - 64;
  double2 te = tab[idx];
  double c  = kd * 0.015625;
  double s  = (t - c) * te.y;
  double p  = fma(s, -1.0/6.0, 0.2);
  p = fma(p, s, -0.25);
  p = fma(p, s,  1.0/3.0);
  p = fma(p, s, -0.5);
  p = fma(p, s,  1.0);
  p = p * s;
  return (float)(te.x + p);
}

// sigmoid-CE, numpy op order  [exact]. noinline: 8 fallback sites share 1 copy.
__device__ __attribute__((noinline)) float ce32(float l, float label,
                                                const double2* tab) {
  float t3 = __fsub_rn(fmaxf(l, 0.0f), __fmul_rn(l, label));
  return __fadd_rn(t3, np_log1pf(np_expf(-fabsf(l)), tab));
}

// Exact decision u < prob  [exact/fallback path]
__device__ __forceinline__ bool decide(float u, float ez) {
  float w = __fadd_rn(1.0f, ez);
  float d = __builtin_fmaf(u, w, -1.0f);
  if (__builtin_expect(fabsf(d) < 1e-5f, 0)) {
    float prob = __fdiv_rn(1.0f, w);
    return u < prob;
  }
  return d < 0.0f;
}

// lane data movement (bitwise-safe)
template<int CTRL> __device__ __forceinline__ float dppx(float v) {
  return __int_as_float(__builtin_amdgcn_mov_dpp(__float_as_int(v), CTRL, 0xF, 0xF, true));
}
__device__ __forceinline__ float rdl(float v, int l) {
  return __int_as_float(__builtin_amdgcn_readlane(__float_as_int(v), l));
}

// numpy pairwise sum over 10 on lanes 0..9  [exact/fallback]
__device__ __forceinline__ float sum10(float c) {
  float c0 = rdl(c, 0), c1 = rdl(c, 1), c2 = rdl(c, 2), c3 = rdl(c, 3);
  float c4 = rdl(c, 4), c5 = rdl(c, 5), c6 = rdl(c, 6), c7 = rdl(c, 7);
  float c8 = rdl(c, 8), c9 = rdl(c, 9);
  float t = __fadd_rn(__fadd_rn(__fadd_rn(c0, c1), __fadd_rn(c2, c3)),
                      __fadd_rn(__fadd_rn(c4, c5), __fadd_rn(c6, c7)));
  t = __fadd_rn(t, c8);
  t = __fadd_rn(t, c9);
  return t;
}

// numpy pairwise sum over 256 children via LDS transpose  [exact/fallback]
__device__ __forceinline__ float fold256_lds(const float c[4], float* __restrict__ scrw,
                                             int idx, int g) {
  *reinterpret_cast<float4*>(scrw + idx * 20 + 4 * g) = make_float4(c[0], c[1], c[2], c[3]);
  const float4* rp = reinterpret_cast<const float4*>(scrw + idx * 20);
  float4 q0 = rp[0], q1 = rp[1], q2 = rp[2], q3 = rp[3];
  float r = q0.x;
  r = __fadd_rn(r, q0.y); r = __fadd_rn(r, q0.z); r = __fadd_rn(r, q0.w);
  r = __fadd_rn(r, q1.x); r = __fadd_rn(r, q1.y); r = __fadd_rn(r, q1.z); r = __fadd_rn(r, q1.w);
  r = __fadd_rn(r, q2.x); r = __fadd_rn(r, q2.y); r = __fadd_rn(r, q2.z); r = __fadd_rn(r, q2.w);
  r = __fadd_rn(r, q3.x); r = __fadd_rn(r, q3.y); r = __fadd_rn(r, q3.z); r = __fadd_rn(r, q3.w);
  r = __fadd_rn(r, dppx<0xB1>(r));
  r = __fadd_rn(r, dppx<0x4E>(r));
  float B0 = rdl(r, 0), B1 = rdl(r, 4), B2 = rdl(r, 8), B3 = rdl(r, 12);
  return __fadd_rn(__fadd_rn(B0, B1), __fadd_rn(B2, B3));
}

// ---- FAST path helpers ------------------------------------------------------
__device__ __forceinline__ float fast_sum256(float loc) {
  float r = loc;
  r = r + dppx<0xB1>(r);                  // quad xor 1
  r = r + dppx<0x4E>(r);                  // quad xor 2
  r = r + dppx<0x124>(r);                 // row_ror:4
  r = r + dppx<0x128>(r);                 // row_ror:8
  r = r + dppx<0x142>(r);                 // row_bcast15
  r = r + dppx<0x143>(r);                 // row_bcast31
  return rdl(r, 63);
}
__device__ __forceinline__ float fast_sum10(float loc) {
  float r = loc;
  r = r + dppx<0xB1>(r);
  r = r + dppx<0x4E>(r);
  r = r + dppx<0x124>(r);
  r = r + dppx<0x128>(r);
  return rdl(r, 0);
}

// z-space threshold; NaN for extreme u routes to exact path.
__device__ __forceinline__ float lu_of(float u) {
  if (u < 1e-4f || u > 0.9999f) return __int_as_float(0x7FC00000);
  return __logf(u) - __logf(__fsub_rn(1.0f, u));
}
__device__ __forceinline__ float q_of(float node, float pl, float u) {
  float lu = lu_of(u);
  float pq = __fsub_rn(pl, lu);
  return (node != 0.0f) ? pq : -pq;
}

#define ZBAND 0.05f
#define LN2F  0.6931471805599453f

__global__ __launch_bounds__(256) void stoch_mlp(
    const float* __restrict__ x,  const int* __restrict__ h1,
    const int* __restrict__ h2,   const int* __restrict__ y,
    const float* __restrict__ W1, const float* __restrict__ b1,
    const float* __restrict__ W2, const float* __restrict__ b2,
    const float* __restrict__ Wo, const float* __restrict__ bo,
    const float* __restrict__ u1, const float* __restrict__ u2,
    float* __restrict__ out)
{
  __shared__ Smem sm;
  const int t    = threadIdx.x;
  const int lane = t & 63;
  const int wid  = t >> 6;            // wave id == local batch row
  const int b0   = blockIdx.x * 4;
  const int b    = b0 + wid;

  // ---- phase 1: tables, states, pl1 = x@W1 (BLAS fp32) + packed staging ---
  if (t < 65) {
    double c = (double)(t + 64) * 0.015625;
    sm.tab[t] = make_double2(log(c), 64.0 / (double)(t + 64));
  }
  for (int j = lane; j < HN; j += 64) sm.h2o[wid][j] = (float)h2[b * HN + j];
  if (lane < 16) sm.yv[wid][lane] = (lane < NOUT) ? (float)y[b * NOUT + lane] : 0.0f;
  {
    float a0 = 0.0f, a1 = 0.0f, a2 = 0.0f, a3 = 0.0f;   // sequential-k FMA chains
    const float* x0 = x + (size_t)b0 * DIN;
    float wk[16];                        // 16-deep W1 ring (chain order unchanged)
    #pragma unroll
    for (int i = 0; i < 16; ++i) wk[i] = W1[(size_t)i * HN + t];
    #pragma unroll 16
    for (int k = 0; k < DIN; ++k) {
      float w = wk[k & 15];
      int kp = (k + 16 < DIN) ? (k + 16) : 0;
      wk[k & 15] = W1[(size_t)kp * HN + t];
      a0 = __builtin_fmaf(x0[k],           w, a0);
      a1 = __builtin_fmaf(x0[DIN   + k],   w, a1);
      a2 = __builtin_fmaf(x0[2*DIN + k],   w, a2);
      a3 = __builtin_fmaf(x0[3*DIN + k],   w, a3);
    }
    float bb = b1[t];
    float4 uv = *reinterpret_cast<const float4*>(u1 + (size_t)t * NB + b0);
    float n0 = (float)h1[(b0 + 0) * HN + t];
    float n1 = (float)h1[(b0 + 1) * HN + t];
    float n2 = (float)h1[(b0 + 2) * HN + t];
    float n3 = (float)h1[(b0 + 3) * HN + t];
    float p0 = __fadd_rn(a0, bb), p1v = __fadd_rn(a1, bb);
    float p2v = __fadd_rn(a2, bb), p3 = __fadd_rn(a3, bb);
    sm.sup[0][t] = make_float4(n0, uv.x, p0,  q_of(n0, p0,  uv.x));
    sm.sup[1][t] = make_float4(n1, uv.y, p1v, q_of(n1, p1v, uv.y));
    sm.sup[2][t] = make_float4(n2, uv.z, p2v, q_of(n2, p2v, uv.z));
    sm.sup[3][t] = make_float4(n3, uv.w, p3,  q_of(n3, p3,  uv.w));
  }
  __syncthreads();   // sup + tab + h2o written cross-wave

  const double2* tab = sm.tab;
  float* scrw = &sm.scr[wid][0];

  // nl-init = h1_old @ W2 + b2 (branchless fma == masked chain, 2-deep ring)
  {
    float acc[4] = {0.0f, 0.0f, 0.0f, 0.0f};
    float4 wb[2];
    wb[0] = *reinterpret_cast<const float4*>(W2 + 4*lane);
    wb[1] = *reinterpret_cast<const float4*>(W2 + HN + 4*lane);
    #pragma unroll 2
    for (int j = 0; j < HN; ++j) {
      float4 wf = wb[j & 1];
      int jp = (j + 2) & (HN - 1);
      wb[j & 1] = *reinterpret_cast<const float4*>(W2 + (size_t)jp * HN + 4*lane);
      float nodej = sm.sup[wid][j].x;
      acc[0] = __builtin_fmaf(nodej, wf.x, acc[0]);
      acc[1] = __builtin_fmaf(nodej, wf.y, acc[1]);
      acc[2] = __builtin_fmaf(nodej, wf.z, acc[2]);
      acc[3] = __builtin_fmaf(nodej, wf.w, acc[3]);
    }
    float4 bv = *reinterpret_cast<const float4*>(b2 + 4*lane);
    *reinterpret_cast<float4*>(&sm.tmp[wid][4*lane]) =
        make_float4(__fadd_rn(acc[0], bv.x), __fadd_rn(acc[1], bv.y),
                    __fadd_rn(acc[2], bv.z), __fadd_rn(acc[3], bv.w));
  }
  // tmp wave-private; same-wave DS ordering -> no barrier

  // Prefetch long-latency inputs consumed after the layer-0 scan
  float u2pre[4];
  #pragma unroll
  for (int i = 0; i < 4; ++i) u2pre[i] = u2[(size_t)(4*lane + i) * NB + b];
  float4 bvpre = *reinterpret_cast<const float4*>(b2 + 4*lane);
  const bool lact = (lane < NOUT);
  float bopre = lact ? bo[lane] : 0.0f;

  // ---- phase 2: layer-0 scan (fused with phase-3 GEMM + L1-init GEMM) -----
  const int idx  = lane & 15;
  const int g    = lane >> 4;
  const int half = idx >> 3;
  const int jacc = idx & 7;
  const int kb   = half * 128 + (4 * g) * 8 + jacc;

  float nlv[4], nv[4];
  int   smk[4];
  #pragma unroll
  for (int i = 0; i < 4; ++i) {
    int k = kb + i * 8;
    nlv[i] = sm.tmp[wid][k];
    nv[i]  = sm.h2o[wid][k];
    smk[i] = (nv[i] != 0.0f) ? (int)0x80000000 : 0;
  }
  float S_c;
  {
    float ci[4];                       // exact anchor (once)
    #pragma unroll
    for (int i = 0; i < 4; ++i) ci[i] = ce32(nlv[i], nv[i], tab);
    S_c = fold256_lds(ci, scrw, idx, g);
  }

  float acc3[4] = {0.0f, 0.0f, 0.0f, 0.0f};  // fused phase-3: h1_new @ W2 cols
  float aL1 = 0.0f;                          // fused L1-init: h2_old @ Wo col
  unsigned long long hmask[4];               // h1_new bits (wave-uniform)

  {
    // 2-deep rings: sup, W2 children cols, W2 4lane-cols, Wo col, h2o bcast
    float4 supC = sm.sup[wid][0];
    float4 supN = sm.sup[wid][1];
    float w0[4], w1[4];
    #pragma unroll
    for (int c = 0; c < 4; ++c) {
      w0[c] = W2[kb + c * 8];
      w1[c] = W2[(size_t)HN + kb + c * 8];
    }
    float4 c3c = *reinterpret_cast<const float4*>(W2 + 4*lane);
    float4 c3n = *reinterpret_cast<const float4*>(W2 + HN + 4*lane);
    float woc = lact ? Wo[lane] : 0.0f;
    float won = lact ? Wo[NOUT + lane] : 0.0f;
    float h2c = sm.h2o[wid][0];
    float h2n = sm.h2o[wid][1];

    #pragma unroll
    for (int jo = 0; jo < 4; ++jo) {
      unsigned long long hm = 0ULL;
      #pragma unroll 2
      for (int ji = 0; ji < 64; ++ji) {
        const int j   = jo * 64 + ji;
        const int jn2 = (j + 2) & (HN - 1);           // wrapped prefetch
        float4 supN2 = sm.sup[wid][jn2];
        float wp[4];
        #pragma unroll
        for (int c = 0; c < 4; ++c) wp[c] = W2[(size_t)jn2 * HN + kb + c * 8];
        float4 c3p = *reinterpret_cast<const float4*>(W2 + (size_t)jn2 * HN + 4*lane);
        float wop  = lact ? Wo[jn2 * NOUT + lane] : 0.0f;
        float h2p  = sm.h2o[wid][jn2];

        float node = supC.x, qj = supC.w;
        int ndm = (node != 0.0f) ? (int)0x80000000 : 0;
        float fresh[4], t3v[4], av[4];
        #pragma unroll
        for (int c = 0; c < 4; ++c) {
          float ws = __int_as_float(__float_as_int(w0[c]) ^ ndm);  // exact +/-w
          fresh[c] = __fadd_rn(nlv[c], ws);        // == fl(nlv -/+ w) bitwise
          float sl = __int_as_float(__float_as_int(fresh[c]) ^ smk[c]);
          t3v[c] = fmaxf(sl, 0.0f);                // == max(l,0)-l*label bitwise
          av[c]  = __fadd_rn(1.0f, __expf(-fabsf(fresh[c])));
        }
        float T    = (t3v[0] + t3v[1]) + (t3v[2] + t3v[3]);
        float prod = (av[0] * av[1]) * (av[2] * av[3]);   // in [1,16]
        float F  = fast_sum256(__builtin_fmaf(LN2F, __log2f(prod), T));
        float dd = (F - S_c) + qj;                 // NaN q -> exact path
        bool nb;
        if (__builtin_expect(!(fabsf(dd) >= ZBAND), 0)) {
          // near-boundary: bitwise numpy replica, both sides
          float one_m = __fsub_rn(1.0f, node);
          float nl0[4], nl1[4], c0i[4], c1i[4];
          #pragma unroll
          for (int c = 0; c < 4; ++c) {
            nl0[c] = __fsub_rn(nlv[c], __fmul_rn(node,  w0[c]));
            nl1[c] = __fadd_rn(nlv[c], __fmul_rn(one_m, w0[c]));
            c0i[c] = ce32(nl0[c], nv[c], tab);
            c1i[c] = ce32(nl1[c], nv[c], tab);
          }
          float S0e = fold256_lds(c0i, scrw, idx, g);
          float S1e = fold256_lds(c1i, scrw, idx, g);
          float ze  = __fsub_rn(__fadd_rn(supC.z, -S1e), -S0e);
          bool nw = decide(supC.y, np_expf(-ze));
          S_c = nw ? S1e : S0e;
          #pragma unroll
          for (int c = 0; c < 4; ++c) nlv[c] = nw ? nl1[c] : nl0[c];
          nb = nw;
        } else {
          bool flip = dd < 0.0f;                   // provably == reference flip
          S_c = flip ? F : S_c;
          #pragma unroll
          for (int c = 0; c < 4; ++c) nlv[c] = flip ? fresh[c] : nlv[c];
          nb = flip ? (node == 0.0f) : (node != 0.0f);
        }
        float nbf = nb ? 1.0f : 0.0f;
        // fused phase-3 accumulation (same chain order as standalone loop)
        acc3[0] = __builtin_fmaf(nbf, c3c.x, acc3[0]);
        acc3[1] = __builtin_fmaf(nbf, c3c.y, acc3[1]);
        acc3[2] = __builtin_fmaf(nbf, c3c.z, acc3[2]);
        acc3[3] = __builtin_fmaf(nbf, c3c.w, acc3[3]);
        // fused L1-init accumulation (same chain order as standalone loop)
        aL1 = __builtin_fmaf(h2c, woc, aL1);
        hm = (hm >> 1) | ((unsigned long long)(nb ? 1 : 0) << 63);
        // rotate rings
        supC = supN; supN = supN2;
        #pragma unroll
        for (int c = 0; c < 4; ++c) { w0[c] = w1[c]; w1[c] = wp[c]; }
        c3c = c3n; c3n = c3p;
        woc = won; won = wop;
        h2c = h2n; h2n = h2p;
      }
      hmask[jo] = hm;
    }
  }

  // ---- phase 3 remainder: finish pl2; repack staging ----------------------
  {
    float p2[4] = {__fadd_rn(acc3[0], bvpre.x), __fadd_rn(acc3[1], bvpre.y),
                   __fadd_rn(acc3[2], bvpre.z), __fadd_rn(acc3[3], bvpre.w)};
    #pragma unroll
    for (int i = 0; i < 4; ++i) {
      int j = 4 * lane + i;
      float nodej = sm.h2o[wid][j];
      sm.sup[wid][j] = make_float4(nodej, u2pre[i], p2[i], q_of(nodej, p2[i], u2pre[i]));
    }
  }

  // layer-1 init remainder
  float nvy = lact ? sm.yv[wid][lane] : 0.0f;
  float nlo = __fadd_rn(aL1, bopre);
  float S_c1 = sum10(lact ? ce32(nlo, nvy, tab) : 0.0f);
  const int syk = (nvy != 0.0f) ? (int)0x80000000 : 0;

  // ---- phase 4: layer-1 scan (10 children on lanes 0..9), masked output ---
  unsigned long long omask[4];
  {
    float4 supC = sm.sup[wid][0];
    float4 supN = sm.sup[wid][1];
    float w0s = lact ? Wo[lane] : 0.0f;
    float w1s = lact ? Wo[NOUT + lane] : 0.0f;
    #pragma unroll
    for (int jo = 0; jo < 4; ++jo) {
      unsigned long long om = 0ULL;
      #pragma unroll 2
      for (int ji = 0; ji < 64; ++ji) {
        const int j   = jo * 64 + ji;
        const int jn2 = (j + 2) & (HN - 1);
        float4 supN2 = sm.sup[wid][jn2];
        float wps = lact ? Wo[jn2 * NOUT + lane] : 0.0f;

        float node = supC.x, qj = supC.w;
        int ndm = (node != 0.0f) ? (int)0x80000000 : 0;
        float ws = __int_as_float(__float_as_int(w0s) ^ ndm);
        float fresh = __fadd_rn(nlo, ws);
        float sl = __int_as_float(__float_as_int(fresh) ^ syk);
        float t3 = fmaxf(sl, 0.0f);
        float p  = __log2f(__fadd_rn(1.0f, __expf(-fabsf(fresh))));
        float loc = lact ? __builtin_fmaf(LN2F, p, t3) : 0.0f;
        float F  = fast_sum10(loc);
        float dd = (F - S_c1) + qj;
        bool nb;
        if (__builtin_expect(!(fabsf(dd) >= ZBAND), 0)) {
          float one_m = __fsub_rn(1.0f, node);
          float nl0 = __fsub_rn(nlo, __fmul_rn(node,  w0s));
          float nl1 = __fadd_rn(nlo, __fmul_rn(one_m, w0s));
          float c0 = lact ? ce32(nl0, nvy, tab) : 0.0f;
          float c1 = lact ? ce32(nl1, nvy, tab) : 0.0f;
          float S0e = sum10(c0);
          float S1e = sum10(c1);
          float ze  = __fsub_rn(__fadd_rn(supC.z, -S1e), -S0e);
          bool nw = decide(supC.y, np_expf(-ze));
          S_c1 = nw ? S1e : S0e;
          nlo  = nw ? nl1 : nl0;
          nb = nw;
        } else {
          bool flip = dd < 0.0f;
          S_c1 = flip ? F : S_c1;
          nlo  = flip ? fresh : nlo;
          nb = flip ? (node == 0.0f) : (node != 0.0f);
        }
        om = (om >> 1) | ((unsigned long long)(nb ? 1 : 0) << 63);
        supC = supN; supN = supN2;
        w0s = w1s; w1s = wps;
      }
      omask[jo] = om;
    }
  }

  // ---- phase 5: outputs from register masks -------------------------------
  float* orow = out + (size_t)b * OSTR;
  #pragma unroll
  for (int q4 = 0; q4 < 4; ++q4) {
    int j = q4 * 64 + lane;               // bit index within block == lane
    orow[j]      = (float)((hmask[q4] >> lane) & 1ULL);
    orow[HN + j] = (float)((omask[q4] >> lane) & 1ULL);
  }
  if (lact) orow[2*HN + lane] = nlo;
}

extern "C" void kernel_launch(void* const* d_in, const int* in_sizes, int n_in,
                              void* d_out, int out_size, void* d_ws, size_t ws_size,
                              hipStream_t stream) {
  const float* x  = (const float*)d_in[0];
  const int*   h1 = (const int*)  d_in[1];
  const int*   h2 = (const int*)  d_in[2];
  const int*   y  = (const int*)  d_in[3];
  const float* W1 = (const float*)d_in[4];
  const float* b1 = (const float*)d_in[5];
  const float* W2 = (const float*)d_in[6];
  const float* b2 = (const float*)d_in[7];
  const float* Wo = (const float*)d_in[8];
  const float* bo = (const float*)d_in[9];
  const float* u1 = (const float*)d_in[10];
  const float* u2 = (const float*)d_in[11];
  stoch_mlp<<<NB/4, 256, 0, stream>>>(x, h1, h2, y, W1, b1, W2, b2, Wo, bo, u1, u2,
                                      (float*)d_out);
}